// Round 13
// baseline (195.902 us; speedup 1.0000x reference)
//
#include <hip/hip_runtime.h>
#include <hip/hip_bf16.h>

// Swin-V2 window attention, fused. B=2048 windows, N=64 tokens, C=256, H=8, Dh=32.
// R13 = R12 (PASS, 191.7us total) + two latency-regime tweaks, dataflow unchanged:
//   1. #pragma unroll 4 on QKV and proj k-loops (hoist L2-hot weight loads over MFMAs)
//   2. s_setprio(1) around MFMA clusters (T5: waves here are barrier-free/phase-diverse,
//      matching the attn case where it measured +4-7%, not the lockstep-GEMM null)
// EVIDENCE RULES (R3..R11):
//  - never feed MFMA-accumulator-derived values to inline-asm v_cvt_pk_bf16_f32
//    (bit-identical 0.119 absmax R6/R7); f2bf bit-ops are always safe.
//  - never use __launch_bounds__ minWavesPerEU >= 3 (NaN with AND without cvt2).
//  - occupancy is register-capped at 2 blocks/CU (arch VGPR + MFMA acc > 128 total).
//  - deferred-V global x re-read thrashes L2 (R8) — x staged once in LDS instead.
//  - LDS bank analysis (R12): all b128 patterns sit at the 8-dword/bank floor ->
//    conflict counter is the wide-op floor, not a fixable loss. Don't swizzle.
// Layout algebra (mfma_f32_16x16x32_bf16): C/D: col=lane&15, row=(lane>>4)*4+reg;
// A-frag A[lane&15][(lane>>4)*8+j]; B-frag B[(lane>>4)*8+j][lane&15];
// xposeS: out word w at lane(lq,lg) = in[lg>>1][w&1] @ lane lq+16*((lg&1)*2+(w>>1)).

typedef __attribute__((ext_vector_type(8))) short bf16x8;
typedef __attribute__((ext_vector_type(4))) short short4v;
typedef __attribute__((ext_vector_type(4))) float f32x4;

__device__ __forceinline__ unsigned short f2bf(float f) {
  union { float f; unsigned int u; } a; a.f = f;
  return (unsigned short)((a.u + 0x7FFFu + ((a.u >> 16) & 1u)) >> 16);  // RNE
}

// pack two f32 -> u32 of 2 bf16 (lo = first) via pure C bit-ops (acc-safe)
__device__ __forceinline__ unsigned pk2(float lo, float hi) {
  return (unsigned)f2bf(lo) | ((unsigned)f2bf(hi) << 16);
}

// packed f32x2 -> bf16x2, single VALU instr. ONLY safe on plain-VGPR load-path
// values — see EVIDENCE RULES above.
__device__ __forceinline__ unsigned int cvt2(float lo, float hi) {
  unsigned int r;
  asm("v_cvt_pk_bf16_f32 %0, %1, %2" : "=v"(r) : "v"(lo), "v"(hi));
  return r;
}

// 4x4 u32 transpose across stride-16 lane groups via ds_bpermute (__shfl).
// R10/R12-proven (PASS, absmax 0.001953).
__device__ __forceinline__ bf16x8 xposeS(unsigned i00, unsigned i01,
                                         unsigned i10, unsigned i11, int lane) {
  const int lg = lane >> 4;
  const int s0 = (lane & 15) + 32 * (lg & 1);   // source for words 0,1
  const int s1 = s0 + 16;                       // source for words 2,3
  unsigned a00 = __shfl(i00, s0), a01 = __shfl(i01, s0);
  unsigned b00 = __shfl(i10, s0), b01 = __shfl(i11, s0);
  unsigned a02 = __shfl(i00, s1), a03 = __shfl(i01, s1);
  unsigned b02 = __shfl(i10, s1), b03 = __shfl(i11, s1);
  const bool lo = lg < 2;                       // X = lg>>1 selects register
  union { unsigned u[4]; bf16x8 v; } c;
  c.u[0] = lo ? a00 : b00;
  c.u[1] = lo ? a01 : b01;
  c.u[2] = lo ? a02 : b02;
  c.u[3] = lo ? a03 : b03;
  return c.v;
}

// ---------------- CPB MLP table: bt[row][h] (parallel, R9-proven) ----------------
__global__ void cpb_table_kernel(const float* __restrict__ w1, const float* __restrict__ b1,
                                 const float* __restrict__ w2, float* __restrict__ bt)
{
  const int row = blockIdx.x;       // 0..126
  const int lane = threadIdx.x;     // 0..63
  float xr = ((float)row - 63.0f) * (8.0f / 63.0f);
  float sgn = (xr > 0.0f) ? 1.0f : ((xr < 0.0f) ? -1.0f : 0.0f);
  float val = sgn * log2f(fabsf(xr) + 1.0f) * (1.0f / 3.0f);  // /log2(8)
  float acc[8];
  #pragma unroll
  for (int hh = 0; hh < 8; ++hh) acc[hh] = 0.0f;
  #pragma unroll
  for (int jj = 0; jj < 8; ++jj) {
    int j = jj * 64 + lane;
    float hv = fmaxf(val * w1[j] + b1[j], 0.0f);
    #pragma unroll
    for (int hh = 0; hh < 8; ++hh) acc[hh] += hv * w2[hh * 512 + j];
  }
  #pragma unroll
  for (int hh = 0; hh < 8; ++hh) {
    #pragma unroll
    for (int m = 1; m < 64; m <<= 1) acc[hh] += __shfl_xor(acc[hh], m);
  }
  if (lane == 0) {
    #pragma unroll
    for (int hh = 0; hh < 8; ++hh) bt[row * 8 + hh] = acc[hh];
  }
}

// ---- expand (S^T orientation, R10-proven): rpb[h][mt][nt][lane][r] ----
__global__ void cpb_expand_kernel(const float* __restrict__ bt, const float* __restrict__ ls,
                                  float* __restrict__ rpb, float* __restrict__ scale)
{
  const int i = blockIdx.x * 256 + threadIdx.x;   // 0..32767
  const int r = i & 3, lane = (i >> 2) & 63, nt = (i >> 8) & 3, mt = (i >> 10) & 3, hh = i >> 12;
  const int row_i = mt * 16 + (lane & 15);          // query index
  const int col_j = nt * 16 + (lane >> 4) * 4 + r;  // key index
  float b = bt[(row_i - col_j + 63) * 8 + hh];
  rpb[i] = 16.0f / (1.0f + __expf(-b));
  if (i < 8) scale[i] = __expf(fminf(ls[i], 4.605170185988091f));  // ln(100)
}

// ---------------- weight conversion (proven verbatim) ----------------
__global__ void convert_kernel(const float* __restrict__ qw, const float* __restrict__ pw,
                               const float* __restrict__ qb, const float* __restrict__ vb,
                               short* __restrict__ wqkv, short* __restrict__ wproj,
                               float* __restrict__ qkvb)
{
  const int idx = blockIdx.x * 256 + threadIdx.x;
  if (idx < 196608) wqkv[idx] = (short)f2bf(qw[idx]);
  else if (idx - 196608 < 65536) wproj[idx - 196608] = (short)f2bf(pw[idx - 196608]);
  if (idx < 768) qkvb[idx] = (idx < 256) ? qb[idx] : ((idx < 512) ? 0.0f : vb[idx - 512]);
}

// ---------------- fused window attention ----------------
__global__ __launch_bounds__(256, 2) void win_attn_kernel(
    const float* __restrict__ x,
    const short* __restrict__ wqkv,
    const short* __restrict__ wproj,
    const float* __restrict__ qkvb,
    const float* __restrict__ scale,
    const float* __restrict__ rpb,
    const float* __restrict__ projb,
    float* __restrict__ out)
{
  // single 33,792 B buffer: x tile bf16 [token][C] stride 264 during QKV;
  // overlaid by attention-output tile ob (same layout) after the hi loop.
  __shared__ short sbuf[64 * 264];

  const int tid = threadIdx.x;
  const int wid = tid >> 6;
  const int lane = tid & 63;
  const int lq = lane & 15;
  const int lg = lane >> 4;
  const int blk = blockIdx.x;

  const f32x4 fz = {0.0f, 0.0f, 0.0f, 0.0f};

  // ---- stage x tile (64x256 f32 -> bf16 LDS; cvt2 on load path; bank-floor clean) ----
  {
    const int r = tid >> 2;
    const int c0 = (tid & 3) * 64;
    const float4* xg = (const float4*)(x + ((size_t)blk * 64 + r) * 256 + c0);
    short* dst = &sbuf[r * 264 + c0];
    #pragma unroll
    for (int i = 0; i < 16; i += 2) {
      float4 a = xg[i];
      float4 b = xg[i + 1];
      union { unsigned int u[4]; bf16x8 v; } c;
      c.u[0] = cvt2(a.x, a.y); c.u[1] = cvt2(a.z, a.w);
      c.u[2] = cvt2(b.x, b.y); c.u[3] = cvt2(b.z, b.w);
      *(bf16x8*)(dst + i * 4) = c.v;
    }
  }
  __syncthreads();

  f32x4 otk[2][2][4];   // [hi][dt][mt], hi compile-time (R2-proven epilogue hold)

  #pragma unroll
  for (int hi = 0; hi < 2; ++hi) {
    const int h = wid + hi * 4;
    const short* wqb = wqkv + (h * 32 + lq) * 256 + lg * 8;

    // ---- QKV: sq/sk = W · x^T (q^T,k^T C-layout), sv = x · Wv^T (v C-layout) ----
    f32x4 sq[2][4], sk[2][4], sv[4][2];
    #pragma unroll
    for (int i = 0; i < 2; ++i)
      #pragma unroll
      for (int j = 0; j < 4; ++j) { sq[i][j] = fz; sk[i][j] = fz; sv[j][i] = fz; }

    #pragma unroll 4
    for (int ks = 0; ks < 8; ++ks) {
      const int k0 = ks * 32;
      bf16x8 xf[4];
      #pragma unroll
      for (int mt = 0; mt < 4; ++mt)
        xf[mt] = *(const bf16x8*)&sbuf[(mt * 16 + lq) * 264 + k0 + lg * 8];
      bf16x8 wqf[2], wkf[2], wvf[2];
      #pragma unroll
      for (int dt = 0; dt < 2; ++dt) {
        const short* wp = wqb + dt * 4096 + k0;
        wqf[dt] = *(const bf16x8*)wp;
        wkf[dt] = *(const bf16x8*)(wp + 65536);    // +256 rows
        wvf[dt] = *(const bf16x8*)(wp + 131072);   // +512 rows
      }
      __builtin_amdgcn_s_setprio(1);
      #pragma unroll
      for (int dt = 0; dt < 2; ++dt)
        #pragma unroll
        for (int mt = 0; mt < 4; ++mt) {
          sq[dt][mt] = __builtin_amdgcn_mfma_f32_16x16x32_bf16(wqf[dt], xf[mt], sq[dt][mt], 0, 0, 0);
          sk[dt][mt] = __builtin_amdgcn_mfma_f32_16x16x32_bf16(wkf[dt], xf[mt], sk[dt][mt], 0, 0, 0);
          sv[mt][dt] = __builtin_amdgcn_mfma_f32_16x16x32_bf16(xf[mt], wvf[dt], sv[mt][dt], 0, 0, 0);
        }
      __builtin_amdgcn_s_setprio(0);
    }

    bf16x8 qB[4], kA[4], vA[2][2];

    // ---- q: +bias, L2-normalize over d (in-lane 8 + shfl 16/32), pack -> B-frags ----
    {
      float qbias[2][4];
      #pragma unroll
      for (int dt = 0; dt < 2; ++dt)
        #pragma unroll
        for (int r = 0; r < 4; ++r)
          qbias[dt][r] = qkvb[h * 32 + dt * 16 + lg * 4 + r];
      #pragma unroll
      for (int mt = 0; mt < 4; ++mt) {
        float vv[2][4];
        float ss = 0.0f;
        #pragma unroll
        for (int dt = 0; dt < 2; ++dt)
          #pragma unroll
          for (int r = 0; r < 4; ++r) {
            vv[dt][r] = sq[dt][mt][r] + qbias[dt][r];
            ss += vv[dt][r] * vv[dt][r];
          }
        ss += __shfl_xor(ss, 16);
        ss += __shfl_xor(ss, 32);
        float rn = 1.0f / fmaxf(sqrtf(ss), 1e-12f);
        qB[mt] = xposeS(pk2(vv[0][0] * rn, vv[0][1] * rn), pk2(vv[0][2] * rn, vv[0][3] * rn),
                        pk2(vv[1][0] * rn, vv[1][1] * rn), pk2(vv[1][2] * rn, vv[1][3] * rn), lane);
      }
    }
    // ---- k: L2-normalize (bias 0), pack -> A-frags ----
    {
      #pragma unroll
      for (int nt = 0; nt < 4; ++nt) {
        float ss = 0.0f;
        #pragma unroll
        for (int dt = 0; dt < 2; ++dt)
          #pragma unroll
          for (int r = 0; r < 4; ++r) ss += sk[dt][nt][r] * sk[dt][nt][r];
        ss += __shfl_xor(ss, 16);
        ss += __shfl_xor(ss, 32);
        float rn = 1.0f / fmaxf(sqrtf(ss), 1e-12f);
        kA[nt] = xposeS(pk2(sk[0][nt][0] * rn, sk[0][nt][1] * rn), pk2(sk[0][nt][2] * rn, sk[0][nt][3] * rn),
                        pk2(sk[1][nt][0] * rn, sk[1][nt][1] * rn), pk2(sk[1][nt][2] * rn, sk[1][nt][3] * rn), lane);
      }
    }
    // ---- v: +bias, pack -> v^T A-frags vA[dt][kt] ----
    {
      const float vb0 = qkvb[512 + h * 32 + lq];
      const float vb1 = qkvb[512 + h * 32 + 16 + lq];
      unsigned vp[4][2][2];
      #pragma unroll
      for (int mt = 0; mt < 4; ++mt) {
        vp[mt][0][0] = pk2(sv[mt][0][0] + vb0, sv[mt][0][1] + vb0);
        vp[mt][0][1] = pk2(sv[mt][0][2] + vb0, sv[mt][0][3] + vb0);
        vp[mt][1][0] = pk2(sv[mt][1][0] + vb1, sv[mt][1][1] + vb1);
        vp[mt][1][1] = pk2(sv[mt][1][2] + vb1, sv[mt][1][3] + vb1);
      }
      #pragma unroll
      for (int dt = 0; dt < 2; ++dt)
        #pragma unroll
        for (int kt = 0; kt < 2; ++kt)
          vA[dt][kt] = xposeS(vp[2 * kt][dt][0], vp[2 * kt][dt][1],
                              vp[2 * kt + 1][dt][0], vp[2 * kt + 1][dt][1], lane);
    }

    // ---- S^T[key][query] = mfma(kA, qB) ----
    f32x4 sT[4][4];
    __builtin_amdgcn_s_setprio(1);
    #pragma unroll
    for (int nt = 0; nt < 4; ++nt)
      #pragma unroll
      for (int mt = 0; mt < 4; ++mt)
        sT[nt][mt] = __builtin_amdgcn_mfma_f32_16x16x32_bf16(kA[nt], qB[mt], fz, 0, 0, 0);
    __builtin_amdgcn_s_setprio(0);

    // ---- softmax over keys (16 in-lane + shfl 16/32), pack P^T pairs ----
    const float sch = scale[h];
    unsigned pp[4][4][2];   // [mt][nt][c]
    #pragma unroll
    for (int mt = 0; mt < 4; ++mt) {
      f32x4 rp[4];
      #pragma unroll
      for (int nt = 0; nt < 4; ++nt)
        rp[nt] = ((const f32x4*)rpb)[((h * 4 + mt) * 4 + nt) * 64 + lane];
      float ee[4][4];
      float mx = -3.0e38f;
      #pragma unroll
      for (int nt = 0; nt < 4; ++nt)
        #pragma unroll
        for (int r = 0; r < 4; ++r) {
          float vv = sT[nt][mt][r] * sch + rp[nt][r];
          ee[nt][r] = vv;
          mx = fmaxf(mx, vv);
        }
      mx = fmaxf(mx, __shfl_xor(mx, 16));
      mx = fmaxf(mx, __shfl_xor(mx, 32));
      float sm = 0.0f;
      #pragma unroll
      for (int nt = 0; nt < 4; ++nt)
        #pragma unroll
        for (int r = 0; r < 4; ++r) {
          ee[nt][r] = __expf(ee[nt][r] - mx);
          sm += ee[nt][r];
        }
      sm += __shfl_xor(sm, 16);
      sm += __shfl_xor(sm, 32);
      float inv = 1.0f / sm;
      #pragma unroll
      for (int nt = 0; nt < 4; ++nt) {
        pp[mt][nt][0] = pk2(ee[nt][0] * inv, ee[nt][1] * inv);
        pp[mt][nt][1] = pk2(ee[nt][2] * inv, ee[nt][3] * inv);
      }
    }

    // ---- PV: out^T = v^T · P^T -> otk[hi] (held in regs) ----
    #pragma unroll
    for (int dt = 0; dt < 2; ++dt)
      #pragma unroll
      for (int mt = 0; mt < 4; ++mt) otk[hi][dt][mt] = fz;
    #pragma unroll
    for (int kt = 0; kt < 2; ++kt) {
      bf16x8 pB[4];
      #pragma unroll
      for (int mt = 0; mt < 4; ++mt)
        pB[mt] = xposeS(pp[mt][2 * kt][0], pp[mt][2 * kt][1],
                        pp[mt][2 * kt + 1][0], pp[mt][2 * kt + 1][1], lane);
      __builtin_amdgcn_s_setprio(1);
      #pragma unroll
      for (int dt = 0; dt < 2; ++dt)
        #pragma unroll
        for (int mt = 0; mt < 4; ++mt)
          otk[hi][dt][mt] = __builtin_amdgcn_mfma_f32_16x16x32_bf16(vA[dt][kt], pB[mt], otk[hi][dt][mt], 0, 0, 0);
      __builtin_amdgcn_s_setprio(0);
    }
  }  // hi

  // ---- all xb reads done: overlay ob on sbuf (f2bf pack — acc-safe) ----
  __syncthreads();
  #pragma unroll
  for (int hi = 0; hi < 2; ++hi) {
    const int h = wid + hi * 4;
    #pragma unroll
    for (int dt = 0; dt < 2; ++dt)
      #pragma unroll
      for (int mt = 0; mt < 4; ++mt) {
        short4v pk;
        #pragma unroll
        for (int r = 0; r < 4; ++r) pk[r] = (short)f2bf(otk[hi][dt][mt][r]);
        *(short4v*)&sbuf[(mt * 16 + lq) * 264 + h * 32 + dt * 16 + lg * 4] = pk;
      }
  }
  __syncthreads();

  // ---- proj: out = ob · Wp^T + b (wave w -> cols [w*64, w*64+64)) ----
  {
    f32x4 acc[4][4];
    #pragma unroll
    for (int mt = 0; mt < 4; ++mt)
      #pragma unroll
      for (int nt = 0; nt < 4; ++nt) acc[mt][nt] = fz;
    const int c0 = wid * 64;
    #pragma unroll 4
    for (int ks = 0; ks < 8; ++ks) {
      const int k0 = ks * 32;
      bf16x8 a[4], b[4];
      #pragma unroll
      for (int mt = 0; mt < 4; ++mt)
        a[mt] = *(const bf16x8*)&sbuf[(mt * 16 + lq) * 264 + k0 + lg * 8];
      #pragma unroll
      for (int nt = 0; nt < 4; ++nt)
        b[nt] = *(const bf16x8*)&wproj[(c0 + nt * 16 + lq) * 256 + k0 + lg * 8];
      __builtin_amdgcn_s_setprio(1);
      #pragma unroll
      for (int mt = 0; mt < 4; ++mt)
        #pragma unroll
        for (int nt = 0; nt < 4; ++nt)
          acc[mt][nt] = __builtin_amdgcn_mfma_f32_16x16x32_bf16(a[mt], b[nt], acc[mt][nt], 0, 0, 0);
      __builtin_amdgcn_s_setprio(0);
    }
    #pragma unroll
    for (int nt = 0; nt < 4; ++nt) {
      const float pbv = projb[c0 + nt * 16 + lq];
      #pragma unroll
      for (int mt = 0; mt < 4; ++mt)
        #pragma unroll
        for (int r = 0; r < 4; ++r) {
          const int row = mt * 16 + lg * 4 + r;
          out[((size_t)blk * 64 + row) * 256 + c0 + nt * 16 + lq] = acc[mt][nt][r] + pbv;
        }
    }
  }
}

extern "C" void kernel_launch(void* const* d_in, const int* in_sizes, int n_in,
                              void* d_out, int out_size, void* d_ws, size_t ws_size,
                              hipStream_t stream) {
  const float* x     = (const float*)d_in[0];
  const float* qkvw  = (const float*)d_in[1];
  const float* qbias = (const float*)d_in[2];
  const float* vbias = (const float*)d_in[3];
  const float* ls    = (const float*)d_in[4];
  const float* w1    = (const float*)d_in[5];
  const float* b1    = (const float*)d_in[6];
  const float* w2    = (const float*)d_in[7];
  const float* pw    = (const float*)d_in[8];
  const float* pbias = (const float*)d_in[9];
  float* out = (float*)d_out;

  char* ws = (char*)d_ws;
  short* wqkv_bf  = (short*)(ws);                 // 393216 B
  short* wproj_bf = (short*)(ws + 393216);        // 131072 B
  float* rpb      = (float*)(ws + 524288);        // 131072 B
  float* scale    = (float*)(ws + 655360);        // 32 B
  float* qkvb     = (float*)(ws + 655392);        // 3072 B
  float* bt       = (float*)(ws + 658464);        // 4064 B

  cpb_table_kernel<<<dim3(127), dim3(64), 0, stream>>>(w1, b1, w2, bt);
  cpb_expand_kernel<<<dim3(128), dim3(256), 0, stream>>>(bt, ls, rpb, scale);
  convert_kernel<<<dim3(1024), dim3(256), 0, stream>>>(qkvw, pw, qbias, vbias,
                                                       wqkv_bf, wproj_bf, qkvb);
  win_attn_kernel<<<dim3(2048), dim3(256), 0, stream>>>(x, wqkv_bf, wproj_bf, qkvb,
                                                        scale, rpb, pbias, out);
}

// Round 14
// 188.277 us; speedup vs baseline: 1.0405x; 1.0405x over previous
//
#include <hip/hip_runtime.h>
#include <hip/hip_bf16.h>

// Swin-V2 window attention, fused. B=2048 windows, N=64 tokens, C=256, H=8, Dh=32.
// R14 = R12 verbatim (191.7us, PASS) + fused prep launch (cpb_table ∪ convert in
// one kernel; they were independent but stream-serialized). R13's unroll-4/setprio
// tweaks REGRESSED (-2%, MfmaUtil down) and are reverted — compiler's unroll-2
// schedule is the optimum found; don't perturb with pragmas/hints.
// EVIDENCE RULES (R3..R13):
//  - never feed MFMA-accumulator-derived values to inline-asm v_cvt_pk_bf16_f32
//    (bit-identical 0.119 absmax R6/R7); f2bf bit-ops are always safe.
//  - never use __launch_bounds__ minWavesPerEU >= 3 (NaN with AND without cvt2).
//  - occupancy is register-capped at 2 blocks/CU (arch VGPR + MFMA acc > 128 total).
//  - deferred-V global x re-read thrashes L2 (R8) — x staged once in LDS instead.
//  - LDS bank analysis (R12): all b128 patterns sit at the 8-dword/bank floor.
//  - setprio / unroll>2 on this kernel: regression (R13).
// Layout algebra (mfma_f32_16x16x32_bf16): C/D: col=lane&15, row=(lane>>4)*4+reg;
// A-frag A[lane&15][(lane>>4)*8+j]; B-frag B[(lane>>4)*8+j][lane&15];
// xposeS: out word w at lane(lq,lg) = in[lg>>1][w&1] @ lane lq+16*((lg&1)*2+(w>>1)).

typedef __attribute__((ext_vector_type(8))) short bf16x8;
typedef __attribute__((ext_vector_type(4))) short short4v;
typedef __attribute__((ext_vector_type(4))) float f32x4;

__device__ __forceinline__ unsigned short f2bf(float f) {
  union { float f; unsigned int u; } a; a.f = f;
  return (unsigned short)((a.u + 0x7FFFu + ((a.u >> 16) & 1u)) >> 16);  // RNE
}

// pack two f32 -> u32 of 2 bf16 (lo = first) via pure C bit-ops (acc-safe)
__device__ __forceinline__ unsigned pk2(float lo, float hi) {
  return (unsigned)f2bf(lo) | ((unsigned)f2bf(hi) << 16);
}

// packed f32x2 -> bf16x2, single VALU instr. ONLY safe on plain-VGPR load-path
// values — see EVIDENCE RULES above.
__device__ __forceinline__ unsigned int cvt2(float lo, float hi) {
  unsigned int r;
  asm("v_cvt_pk_bf16_f32 %0, %1, %2" : "=v"(r) : "v"(lo), "v"(hi));
  return r;
}

// 4x4 u32 transpose across stride-16 lane groups via ds_bpermute (__shfl).
// R10/R12-proven (PASS, absmax 0.001953).
__device__ __forceinline__ bf16x8 xposeS(unsigned i00, unsigned i01,
                                         unsigned i10, unsigned i11, int lane) {
  const int lg = lane >> 4;
  const int s0 = (lane & 15) + 32 * (lg & 1);   // source for words 0,1
  const int s1 = s0 + 16;                       // source for words 2,3
  unsigned a00 = __shfl(i00, s0), a01 = __shfl(i01, s0);
  unsigned b00 = __shfl(i10, s0), b01 = __shfl(i11, s0);
  unsigned a02 = __shfl(i00, s1), a03 = __shfl(i01, s1);
  unsigned b02 = __shfl(i10, s1), b03 = __shfl(i11, s1);
  const bool lo = lg < 2;                       // X = lg>>1 selects register
  union { unsigned u[4]; bf16x8 v; } c;
  c.u[0] = lo ? a00 : b00;
  c.u[1] = lo ? a01 : b01;
  c.u[2] = lo ? a02 : b02;
  c.u[3] = lo ? a03 : b03;
  return c.v;
}

// ---------------- fused prep: cpb table (blocks 0..126) + weight convert ----------------
__global__ void prep_kernel(const float* __restrict__ w1, const float* __restrict__ b1,
                            const float* __restrict__ w2, float* __restrict__ bt,
                            const float* __restrict__ qw, const float* __restrict__ pw,
                            const float* __restrict__ qb, const float* __restrict__ vb,
                            short* __restrict__ wqkv, short* __restrict__ wproj,
                            float* __restrict__ qkvb)
{
  if (blockIdx.x < 127) {
    // ---- CPB MLP table row (R9-proven body, first wave only) ----
    if (threadIdx.x < 64) {
      const int row = blockIdx.x;       // 0..126
      const int lane = threadIdx.x;     // 0..63
      float xr = ((float)row - 63.0f) * (8.0f / 63.0f);
      float sgn = (xr > 0.0f) ? 1.0f : ((xr < 0.0f) ? -1.0f : 0.0f);
      float val = sgn * log2f(fabsf(xr) + 1.0f) * (1.0f / 3.0f);  // /log2(8)
      float acc[8];
      #pragma unroll
      for (int hh = 0; hh < 8; ++hh) acc[hh] = 0.0f;
      #pragma unroll
      for (int jj = 0; jj < 8; ++jj) {
        int j = jj * 64 + lane;
        float hv = fmaxf(val * w1[j] + b1[j], 0.0f);
        #pragma unroll
        for (int hh = 0; hh < 8; ++hh) acc[hh] += hv * w2[hh * 512 + j];
      }
      #pragma unroll
      for (int hh = 0; hh < 8; ++hh) {
        #pragma unroll
        for (int m = 1; m < 64; m <<= 1) acc[hh] += __shfl_xor(acc[hh], m);
      }
      if (lane == 0) {
        #pragma unroll
        for (int hh = 0; hh < 8; ++hh) bt[row * 8 + hh] = acc[hh];
      }
    }
  } else {
    // ---- weight conversion (proven formulas, re-based index) ----
    const int idx = (blockIdx.x - 127) * 256 + threadIdx.x;
    if (idx < 196608) wqkv[idx] = (short)f2bf(qw[idx]);
    else if (idx - 196608 < 65536) wproj[idx - 196608] = (short)f2bf(pw[idx - 196608]);
    if (idx < 768) qkvb[idx] = (idx < 256) ? qb[idx] : ((idx < 512) ? 0.0f : vb[idx - 512]);
  }
}

// ---- expand (S^T orientation, R10-proven): rpb[h][mt][nt][lane][r] ----
__global__ void cpb_expand_kernel(const float* __restrict__ bt, const float* __restrict__ ls,
                                  float* __restrict__ rpb, float* __restrict__ scale)
{
  const int i = blockIdx.x * 256 + threadIdx.x;   // 0..32767
  const int r = i & 3, lane = (i >> 2) & 63, nt = (i >> 8) & 3, mt = (i >> 10) & 3, hh = i >> 12;
  const int row_i = mt * 16 + (lane & 15);          // query index
  const int col_j = nt * 16 + (lane >> 4) * 4 + r;  // key index
  float b = bt[(row_i - col_j + 63) * 8 + hh];
  rpb[i] = 16.0f / (1.0f + __expf(-b));
  if (i < 8) scale[i] = __expf(fminf(ls[i], 4.605170185988091f));  // ln(100)
}

// ---------------- fused window attention (R12 verbatim, PASS 191.7us) ----------------
__global__ __launch_bounds__(256, 2) void win_attn_kernel(
    const float* __restrict__ x,
    const short* __restrict__ wqkv,
    const short* __restrict__ wproj,
    const float* __restrict__ qkvb,
    const float* __restrict__ scale,
    const float* __restrict__ rpb,
    const float* __restrict__ projb,
    float* __restrict__ out)
{
  // single 33,792 B buffer: x tile bf16 [token][C] stride 264 during QKV;
  // overlaid by attention-output tile ob (same layout) after the hi loop.
  __shared__ short sbuf[64 * 264];

  const int tid = threadIdx.x;
  const int wid = tid >> 6;
  const int lane = tid & 63;
  const int lq = lane & 15;
  const int lg = lane >> 4;
  const int blk = blockIdx.x;

  const f32x4 fz = {0.0f, 0.0f, 0.0f, 0.0f};

  // ---- stage x tile (64x256 f32 -> bf16 LDS; cvt2 on load path; bank-floor clean) ----
  {
    const int r = tid >> 2;
    const int c0 = (tid & 3) * 64;
    const float4* xg = (const float4*)(x + ((size_t)blk * 64 + r) * 256 + c0);
    short* dst = &sbuf[r * 264 + c0];
    #pragma unroll
    for (int i = 0; i < 16; i += 2) {
      float4 a = xg[i];
      float4 b = xg[i + 1];
      union { unsigned int u[4]; bf16x8 v; } c;
      c.u[0] = cvt2(a.x, a.y); c.u[1] = cvt2(a.z, a.w);
      c.u[2] = cvt2(b.x, b.y); c.u[3] = cvt2(b.z, b.w);
      *(bf16x8*)(dst + i * 4) = c.v;
    }
  }
  __syncthreads();

  f32x4 otk[2][2][4];   // [hi][dt][mt], hi compile-time (R2-proven epilogue hold)

  #pragma unroll
  for (int hi = 0; hi < 2; ++hi) {
    const int h = wid + hi * 4;
    const short* wqb = wqkv + (h * 32 + lq) * 256 + lg * 8;

    // ---- QKV: sq/sk = W · x^T (q^T,k^T C-layout), sv = x · Wv^T (v C-layout) ----
    f32x4 sq[2][4], sk[2][4], sv[4][2];
    #pragma unroll
    for (int i = 0; i < 2; ++i)
      #pragma unroll
      for (int j = 0; j < 4; ++j) { sq[i][j] = fz; sk[i][j] = fz; sv[j][i] = fz; }

    #pragma unroll 2
    for (int ks = 0; ks < 8; ++ks) {
      const int k0 = ks * 32;
      bf16x8 xf[4];
      #pragma unroll
      for (int mt = 0; mt < 4; ++mt)
        xf[mt] = *(const bf16x8*)&sbuf[(mt * 16 + lq) * 264 + k0 + lg * 8];
      bf16x8 wqf[2], wkf[2], wvf[2];
      #pragma unroll
      for (int dt = 0; dt < 2; ++dt) {
        const short* wp = wqb + dt * 4096 + k0;
        wqf[dt] = *(const bf16x8*)wp;
        wkf[dt] = *(const bf16x8*)(wp + 65536);    // +256 rows
        wvf[dt] = *(const bf16x8*)(wp + 131072);   // +512 rows
      }
      #pragma unroll
      for (int dt = 0; dt < 2; ++dt)
        #pragma unroll
        for (int mt = 0; mt < 4; ++mt) {
          sq[dt][mt] = __builtin_amdgcn_mfma_f32_16x16x32_bf16(wqf[dt], xf[mt], sq[dt][mt], 0, 0, 0);
          sk[dt][mt] = __builtin_amdgcn_mfma_f32_16x16x32_bf16(wkf[dt], xf[mt], sk[dt][mt], 0, 0, 0);
          sv[mt][dt] = __builtin_amdgcn_mfma_f32_16x16x32_bf16(xf[mt], wvf[dt], sv[mt][dt], 0, 0, 0);
        }
    }

    bf16x8 qB[4], kA[4], vA[2][2];

    // ---- q: +bias, L2-normalize over d (in-lane 8 + shfl 16/32), pack -> B-frags ----
    {
      float qbias[2][4];
      #pragma unroll
      for (int dt = 0; dt < 2; ++dt)
        #pragma unroll
        for (int r = 0; r < 4; ++r)
          qbias[dt][r] = qkvb[h * 32 + dt * 16 + lg * 4 + r];
      #pragma unroll
      for (int mt = 0; mt < 4; ++mt) {
        float vv[2][4];
        float ss = 0.0f;
        #pragma unroll
        for (int dt = 0; dt < 2; ++dt)
          #pragma unroll
          for (int r = 0; r < 4; ++r) {
            vv[dt][r] = sq[dt][mt][r] + qbias[dt][r];
            ss += vv[dt][r] * vv[dt][r];
          }
        ss += __shfl_xor(ss, 16);
        ss += __shfl_xor(ss, 32);
        float rn = 1.0f / fmaxf(sqrtf(ss), 1e-12f);
        qB[mt] = xposeS(pk2(vv[0][0] * rn, vv[0][1] * rn), pk2(vv[0][2] * rn, vv[0][3] * rn),
                        pk2(vv[1][0] * rn, vv[1][1] * rn), pk2(vv[1][2] * rn, vv[1][3] * rn), lane);
      }
    }
    // ---- k: L2-normalize (bias 0), pack -> A-frags ----
    {
      #pragma unroll
      for (int nt = 0; nt < 4; ++nt) {
        float ss = 0.0f;
        #pragma unroll
        for (int dt = 0; dt < 2; ++dt)
          #pragma unroll
          for (int r = 0; r < 4; ++r) ss += sk[dt][nt][r] * sk[dt][nt][r];
        ss += __shfl_xor(ss, 16);
        ss += __shfl_xor(ss, 32);
        float rn = 1.0f / fmaxf(sqrtf(ss), 1e-12f);
        kA[nt] = xposeS(pk2(sk[0][nt][0] * rn, sk[0][nt][1] * rn), pk2(sk[0][nt][2] * rn, sk[0][nt][3] * rn),
                        pk2(sk[1][nt][0] * rn, sk[1][nt][1] * rn), pk2(sk[1][nt][2] * rn, sk[1][nt][3] * rn), lane);
      }
    }
    // ---- v: +bias, pack -> v^T A-frags vA[dt][kt] ----
    {
      const float vb0 = qkvb[512 + h * 32 + lq];
      const float vb1 = qkvb[512 + h * 32 + 16 + lq];
      unsigned vp[4][2][2];
      #pragma unroll
      for (int mt = 0; mt < 4; ++mt) {
        vp[mt][0][0] = pk2(sv[mt][0][0] + vb0, sv[mt][0][1] + vb0);
        vp[mt][0][1] = pk2(sv[mt][0][2] + vb0, sv[mt][0][3] + vb0);
        vp[mt][1][0] = pk2(sv[mt][1][0] + vb1, sv[mt][1][1] + vb1);
        vp[mt][1][1] = pk2(sv[mt][1][2] + vb1, sv[mt][1][3] + vb1);
      }
      #pragma unroll
      for (int dt = 0; dt < 2; ++dt)
        #pragma unroll
        for (int kt = 0; kt < 2; ++kt)
          vA[dt][kt] = xposeS(vp[2 * kt][dt][0], vp[2 * kt][dt][1],
                              vp[2 * kt + 1][dt][0], vp[2 * kt + 1][dt][1], lane);
    }

    // ---- S^T[key][query] = mfma(kA, qB) ----
    f32x4 sT[4][4];
    #pragma unroll
    for (int nt = 0; nt < 4; ++nt)
      #pragma unroll
      for (int mt = 0; mt < 4; ++mt)
        sT[nt][mt] = __builtin_amdgcn_mfma_f32_16x16x32_bf16(kA[nt], qB[mt], fz, 0, 0, 0);

    // ---- softmax over keys (16 in-lane + shfl 16/32), pack P^T pairs ----
    const float sch = scale[h];
    unsigned pp[4][4][2];   // [mt][nt][c]
    #pragma unroll
    for (int mt = 0; mt < 4; ++mt) {
      f32x4 rp[4];
      #pragma unroll
      for (int nt = 0; nt < 4; ++nt)
        rp[nt] = ((const f32x4*)rpb)[((h * 4 + mt) * 4 + nt) * 64 + lane];
      float ee[4][4];
      float mx = -3.0e38f;
      #pragma unroll
      for (int nt = 0; nt < 4; ++nt)
        #pragma unroll
        for (int r = 0; r < 4; ++r) {
          float vv = sT[nt][mt][r] * sch + rp[nt][r];
          ee[nt][r] = vv;
          mx = fmaxf(mx, vv);
        }
      mx = fmaxf(mx, __shfl_xor(mx, 16));
      mx = fmaxf(mx, __shfl_xor(mx, 32));
      float sm = 0.0f;
      #pragma unroll
      for (int nt = 0; nt < 4; ++nt)
        #pragma unroll
        for (int r = 0; r < 4; ++r) {
          ee[nt][r] = __expf(ee[nt][r] - mx);
          sm += ee[nt][r];
        }
      sm += __shfl_xor(sm, 16);
      sm += __shfl_xor(sm, 32);
      float inv = 1.0f / sm;
      #pragma unroll
      for (int nt = 0; nt < 4; ++nt) {
        pp[mt][nt][0] = pk2(ee[nt][0] * inv, ee[nt][1] * inv);
        pp[mt][nt][1] = pk2(ee[nt][2] * inv, ee[nt][3] * inv);
      }
    }

    // ---- PV: out^T = v^T · P^T -> otk[hi] (held in regs) ----
    #pragma unroll
    for (int dt = 0; dt < 2; ++dt)
      #pragma unroll
      for (int mt = 0; mt < 4; ++mt) otk[hi][dt][mt] = fz;
    #pragma unroll
    for (int kt = 0; kt < 2; ++kt) {
      bf16x8 pB[4];
      #pragma unroll
      for (int mt = 0; mt < 4; ++mt)
        pB[mt] = xposeS(pp[mt][2 * kt][0], pp[mt][2 * kt][1],
                        pp[mt][2 * kt + 1][0], pp[mt][2 * kt + 1][1], lane);
      #pragma unroll
      for (int dt = 0; dt < 2; ++dt)
        #pragma unroll
        for (int mt = 0; mt < 4; ++mt)
          otk[hi][dt][mt] = __builtin_amdgcn_mfma_f32_16x16x32_bf16(vA[dt][kt], pB[mt], otk[hi][dt][mt], 0, 0, 0);
    }
  }  // hi

  // ---- all xb reads done: overlay ob on sbuf (f2bf pack — acc-safe) ----
  __syncthreads();
  #pragma unroll
  for (int hi = 0; hi < 2; ++hi) {
    const int h = wid + hi * 4;
    #pragma unroll
    for (int dt = 0; dt < 2; ++dt)
      #pragma unroll
      for (int mt = 0; mt < 4; ++mt) {
        short4v pk;
        #pragma unroll
        for (int r = 0; r < 4; ++r) pk[r] = (short)f2bf(otk[hi][dt][mt][r]);
        *(short4v*)&sbuf[(mt * 16 + lq) * 264 + h * 32 + dt * 16 + lg * 4] = pk;
      }
  }
  __syncthreads();

  // ---- proj: out = ob · Wp^T + b (wave w -> cols [w*64, w*64+64)) ----
  {
    f32x4 acc[4][4];
    #pragma unroll
    for (int mt = 0; mt < 4; ++mt)
      #pragma unroll
      for (int nt = 0; nt < 4; ++nt) acc[mt][nt] = fz;
    const int c0 = wid * 64;
    #pragma unroll 2
    for (int ks = 0; ks < 8; ++ks) {
      const int k0 = ks * 32;
      bf16x8 a[4], b[4];
      #pragma unroll
      for (int mt = 0; mt < 4; ++mt)
        a[mt] = *(const bf16x8*)&sbuf[(mt * 16 + lq) * 264 + k0 + lg * 8];
      #pragma unroll
      for (int nt = 0; nt < 4; ++nt)
        b[nt] = *(const bf16x8*)&wproj[(c0 + nt * 16 + lq) * 256 + k0 + lg * 8];
      #pragma unroll
      for (int mt = 0; mt < 4; ++mt)
        #pragma unroll
        for (int nt = 0; nt < 4; ++nt)
          acc[mt][nt] = __builtin_amdgcn_mfma_f32_16x16x32_bf16(a[mt], b[nt], acc[mt][nt], 0, 0, 0);
    }
    #pragma unroll
    for (int nt = 0; nt < 4; ++nt) {
      const float pbv = projb[c0 + nt * 16 + lq];
      #pragma unroll
      for (int mt = 0; mt < 4; ++mt)
        #pragma unroll
        for (int r = 0; r < 4; ++r) {
          const int row = mt * 16 + lg * 4 + r;
          out[((size_t)blk * 64 + row) * 256 + c0 + nt * 16 + lq] = acc[mt][nt][r] + pbv;
        }
    }
  }
}

extern "C" void kernel_launch(void* const* d_in, const int* in_sizes, int n_in,
                              void* d_out, int out_size, void* d_ws, size_t ws_size,
                              hipStream_t stream) {
  const float* x     = (const float*)d_in[0];
  const float* qkvw  = (const float*)d_in[1];
  const float* qbias = (const float*)d_in[2];
  const float* vbias = (const float*)d_in[3];
  const float* ls    = (const float*)d_in[4];
  const float* w1    = (const float*)d_in[5];
  const float* b1    = (const float*)d_in[6];
  const float* w2    = (const float*)d_in[7];
  const float* pw    = (const float*)d_in[8];
  const float* pbias = (const float*)d_in[9];
  float* out = (float*)d_out;

  char* ws = (char*)d_ws;
  short* wqkv_bf  = (short*)(ws);                 // 393216 B
  short* wproj_bf = (short*)(ws + 393216);        // 131072 B
  float* rpb      = (float*)(ws + 524288);        // 131072 B
  float* scale    = (float*)(ws + 655360);        // 32 B
  float* qkvb     = (float*)(ws + 655392);        // 3072 B
  float* bt       = (float*)(ws + 658464);        // 4064 B

  prep_kernel<<<dim3(1151), dim3(256), 0, stream>>>(w1, b1, w2, bt,
                                                    qkvw, pw, qbias, vbias,
                                                    wqkv_bf, wproj_bf, qkvb);
  cpb_expand_kernel<<<dim3(128), dim3(256), 0, stream>>>(bt, ls, rpb, scale);
  win_attn_kernel<<<dim3(2048), dim3(256), 0, stream>>>(x, wqkv_bf, wproj_bf, qkvb,
                                                        scale, rpb, pbias, out);
}

// Round 15
// 184.181 us; speedup vs baseline: 1.0636x; 1.0222x over previous
//
#include <hip/hip_runtime.h>
#include <hip/hip_bf16.h>

// Swin-V2 window attention, fused. B=2048 windows, N=64 tokens, C=256, H=8, Dh=32.
// R15 = R14 (188.3us, PASS) + two VALU-diet changes on the serial chain:
//   1. accumulator bf16 packs via compiler-native __float22bfloat162_rn (RNE,
//      no inline asm -> compiler handles AGPR moves; replaces ~9-op f2bf/pk2)
//   2. deferred softmax normalization: pack P unnormalized, scale otk by inv[mt]
//      after PV (out = (P·V)/sm) — 64 mults -> 32 per head, numerics-equivalent
// EVIDENCE RULES (R3..R13):
//  - never feed MFMA-accumulator-derived values to INLINE-ASM v_cvt_pk_bf16_f32
//    (bit-identical 0.119 absmax R6/R7). Compiler-generated conversions on
//    accumulator values are safe (f2bf R9, shfl R10, native casts here).
//  - never use __launch_bounds__ minWavesPerEU >= 3 (NaN with AND without cvt2).
//  - occupancy is register-capped at 2 blocks/CU (arch VGPR + MFMA acc > 170).
//  - deferred-V global x re-read thrashes L2 (R8) — x staged once in LDS instead.
//  - LDS bank analysis (R12): all b128 patterns sit at the 8-dword/bank floor.
//  - setprio / unroll>2 on this kernel: regression (R13).
// Layout algebra (mfma_f32_16x16x32_bf16): C/D: col=lane&15, row=(lane>>4)*4+reg;
// A-frag A[lane&15][(lane>>4)*8+j]; B-frag B[(lane>>4)*8+j][lane&15];
// xposeS: out word w at lane(lq,lg) = in[lg>>1][w&1] @ lane lq+16*((lg&1)*2+(w>>1)).

typedef __attribute__((ext_vector_type(8))) short bf16x8;
typedef __attribute__((ext_vector_type(4))) short short4v;
typedef __attribute__((ext_vector_type(4))) float f32x4;

__device__ __forceinline__ unsigned short f2bf(float f) {
  union { float f; unsigned int u; } a; a.f = f;
  return (unsigned short)((a.u + 0x7FFFu + ((a.u >> 16) & 1u)) >> 16);  // RNE
}

// compiler-native packed f32x2 -> bf16x2 (RNE, lo = first/low 16b). Safe on
// accumulator values: no inline asm, compiler manages register classes.
__device__ __forceinline__ unsigned pkc(float lo, float hi) {
  float2 f; f.x = lo; f.y = hi;
  __hip_bfloat162 h = __float22bfloat162_rn(f);
  union { __hip_bfloat162 h; unsigned u; } c; c.h = h;
  return c.u;
}

// packed f32x2 -> bf16x2 inline asm, single VALU instr. ONLY safe on plain-VGPR
// load-path values — see EVIDENCE RULES above.
__device__ __forceinline__ unsigned int cvt2(float lo, float hi) {
  unsigned int r;
  asm("v_cvt_pk_bf16_f32 %0, %1, %2" : "=v"(r) : "v"(lo), "v"(hi));
  return r;
}

// 4x4 u32 transpose across stride-16 lane groups via ds_bpermute (__shfl).
// R10/R12-proven (PASS, absmax 0.001953).
__device__ __forceinline__ bf16x8 xposeS(unsigned i00, unsigned i01,
                                         unsigned i10, unsigned i11, int lane) {
  const int lg = lane >> 4;
  const int s0 = (lane & 15) + 32 * (lg & 1);   // source for words 0,1
  const int s1 = s0 + 16;                       // source for words 2,3
  unsigned a00 = __shfl(i00, s0), a01 = __shfl(i01, s0);
  unsigned b00 = __shfl(i10, s0), b01 = __shfl(i11, s0);
  unsigned a02 = __shfl(i00, s1), a03 = __shfl(i01, s1);
  unsigned b02 = __shfl(i10, s1), b03 = __shfl(i11, s1);
  const bool lo = lg < 2;                       // X = lg>>1 selects register
  union { unsigned u[4]; bf16x8 v; } c;
  c.u[0] = lo ? a00 : b00;
  c.u[1] = lo ? a01 : b01;
  c.u[2] = lo ? a02 : b02;
  c.u[3] = lo ? a03 : b03;
  return c.v;
}

// ---------------- fused prep: cpb table (blocks 0..126) + weight convert ----------------
__global__ void prep_kernel(const float* __restrict__ w1, const float* __restrict__ b1,
                            const float* __restrict__ w2, float* __restrict__ bt,
                            const float* __restrict__ qw, const float* __restrict__ pw,
                            const float* __restrict__ qb, const float* __restrict__ vb,
                            short* __restrict__ wqkv, short* __restrict__ wproj,
                            float* __restrict__ qkvb)
{
  if (blockIdx.x < 127) {
    // ---- CPB MLP table row (R9-proven body, first wave only) ----
    if (threadIdx.x < 64) {
      const int row = blockIdx.x;       // 0..126
      const int lane = threadIdx.x;     // 0..63
      float xr = ((float)row - 63.0f) * (8.0f / 63.0f);
      float sgn = (xr > 0.0f) ? 1.0f : ((xr < 0.0f) ? -1.0f : 0.0f);
      float val = sgn * log2f(fabsf(xr) + 1.0f) * (1.0f / 3.0f);  // /log2(8)
      float acc[8];
      #pragma unroll
      for (int hh = 0; hh < 8; ++hh) acc[hh] = 0.0f;
      #pragma unroll
      for (int jj = 0; jj < 8; ++jj) {
        int j = jj * 64 + lane;
        float hv = fmaxf(val * w1[j] + b1[j], 0.0f);
        #pragma unroll
        for (int hh = 0; hh < 8; ++hh) acc[hh] += hv * w2[hh * 512 + j];
      }
      #pragma unroll
      for (int hh = 0; hh < 8; ++hh) {
        #pragma unroll
        for (int m = 1; m < 64; m <<= 1) acc[hh] += __shfl_xor(acc[hh], m);
      }
      if (lane == 0) {
        #pragma unroll
        for (int hh = 0; hh < 8; ++hh) bt[row * 8 + hh] = acc[hh];
      }
    }
  } else {
    // ---- weight conversion (proven formulas, re-based index) ----
    const int idx = (blockIdx.x - 127) * 256 + threadIdx.x;
    if (idx < 196608) wqkv[idx] = (short)f2bf(qw[idx]);
    else if (idx - 196608 < 65536) wproj[idx - 196608] = (short)f2bf(pw[idx - 196608]);
    if (idx < 768) qkvb[idx] = (idx < 256) ? qb[idx] : ((idx < 512) ? 0.0f : vb[idx - 512]);
  }
}

// ---- expand (S^T orientation, R10-proven): rpb[h][mt][nt][lane][r] ----
__global__ void cpb_expand_kernel(const float* __restrict__ bt, const float* __restrict__ ls,
                                  float* __restrict__ rpb, float* __restrict__ scale)
{
  const int i = blockIdx.x * 256 + threadIdx.x;   // 0..32767
  const int r = i & 3, lane = (i >> 2) & 63, nt = (i >> 8) & 3, mt = (i >> 10) & 3, hh = i >> 12;
  const int row_i = mt * 16 + (lane & 15);          // query index
  const int col_j = nt * 16 + (lane >> 4) * 4 + r;  // key index
  float b = bt[(row_i - col_j + 63) * 8 + hh];
  rpb[i] = 16.0f / (1.0f + __expf(-b));
  if (i < 8) scale[i] = __expf(fminf(ls[i], 4.605170185988091f));  // ln(100)
}

// ---------------- fused window attention ----------------
__global__ __launch_bounds__(256, 2) void win_attn_kernel(
    const float* __restrict__ x,
    const short* __restrict__ wqkv,
    const short* __restrict__ wproj,
    const float* __restrict__ qkvb,
    const float* __restrict__ scale,
    const float* __restrict__ rpb,
    const float* __restrict__ projb,
    float* __restrict__ out)
{
  // single 33,792 B buffer: x tile bf16 [token][C] stride 264 during QKV;
  // overlaid by attention-output tile ob (same layout) after the hi loop.
  __shared__ short sbuf[64 * 264];

  const int tid = threadIdx.x;
  const int wid = tid >> 6;
  const int lane = tid & 63;
  const int lq = lane & 15;
  const int lg = lane >> 4;
  const int blk = blockIdx.x;

  const f32x4 fz = {0.0f, 0.0f, 0.0f, 0.0f};

  // ---- stage x tile (64x256 f32 -> bf16 LDS; cvt2 on load path; bank-floor clean) ----
  {
    const int r = tid >> 2;
    const int c0 = (tid & 3) * 64;
    const float4* xg = (const float4*)(x + ((size_t)blk * 64 + r) * 256 + c0);
    short* dst = &sbuf[r * 264 + c0];
    #pragma unroll
    for (int i = 0; i < 16; i += 2) {
      float4 a = xg[i];
      float4 b = xg[i + 1];
      union { unsigned int u[4]; bf16x8 v; } c;
      c.u[0] = cvt2(a.x, a.y); c.u[1] = cvt2(a.z, a.w);
      c.u[2] = cvt2(b.x, b.y); c.u[3] = cvt2(b.z, b.w);
      *(bf16x8*)(dst + i * 4) = c.v;
    }
  }
  __syncthreads();

  f32x4 otk[2][2][4];   // [hi][dt][mt], hi compile-time (R2-proven epilogue hold)

  #pragma unroll
  for (int hi = 0; hi < 2; ++hi) {
    const int h = wid + hi * 4;
    const short* wqb = wqkv + (h * 32 + lq) * 256 + lg * 8;

    // ---- QKV: sq/sk = W · x^T (q^T,k^T C-layout), sv = x · Wv^T (v C-layout) ----
    f32x4 sq[2][4], sk[2][4], sv[4][2];
    #pragma unroll
    for (int i = 0; i < 2; ++i)
      #pragma unroll
      for (int j = 0; j < 4; ++j) { sq[i][j] = fz; sk[i][j] = fz; sv[j][i] = fz; }

    #pragma unroll 2
    for (int ks = 0; ks < 8; ++ks) {
      const int k0 = ks * 32;
      bf16x8 xf[4];
      #pragma unroll
      for (int mt = 0; mt < 4; ++mt)
        xf[mt] = *(const bf16x8*)&sbuf[(mt * 16 + lq) * 264 + k0 + lg * 8];
      bf16x8 wqf[2], wkf[2], wvf[2];
      #pragma unroll
      for (int dt = 0; dt < 2; ++dt) {
        const short* wp = wqb + dt * 4096 + k0;
        wqf[dt] = *(const bf16x8*)wp;
        wkf[dt] = *(const bf16x8*)(wp + 65536);    // +256 rows
        wvf[dt] = *(const bf16x8*)(wp + 131072);   // +512 rows
      }
      #pragma unroll
      for (int dt = 0; dt < 2; ++dt)
        #pragma unroll
        for (int mt = 0; mt < 4; ++mt) {
          sq[dt][mt] = __builtin_amdgcn_mfma_f32_16x16x32_bf16(wqf[dt], xf[mt], sq[dt][mt], 0, 0, 0);
          sk[dt][mt] = __builtin_amdgcn_mfma_f32_16x16x32_bf16(wkf[dt], xf[mt], sk[dt][mt], 0, 0, 0);
          sv[mt][dt] = __builtin_amdgcn_mfma_f32_16x16x32_bf16(xf[mt], wvf[dt], sv[mt][dt], 0, 0, 0);
        }
    }

    bf16x8 qB[4], kA[4], vA[2][2];

    // ---- q: +bias, L2-normalize over d (in-lane 8 + shfl 16/32), pack -> B-frags ----
    {
      float qbias[2][4];
      #pragma unroll
      for (int dt = 0; dt < 2; ++dt)
        #pragma unroll
        for (int r = 0; r < 4; ++r)
          qbias[dt][r] = qkvb[h * 32 + dt * 16 + lg * 4 + r];
      #pragma unroll
      for (int mt = 0; mt < 4; ++mt) {
        float vv[2][4];
        float ss = 0.0f;
        #pragma unroll
        for (int dt = 0; dt < 2; ++dt)
          #pragma unroll
          for (int r = 0; r < 4; ++r) {
            vv[dt][r] = sq[dt][mt][r] + qbias[dt][r];
            ss += vv[dt][r] * vv[dt][r];
          }
        ss += __shfl_xor(ss, 16);
        ss += __shfl_xor(ss, 32);
        float rn = 1.0f / fmaxf(sqrtf(ss), 1e-12f);
        qB[mt] = xposeS(pkc(vv[0][0] * rn, vv[0][1] * rn), pkc(vv[0][2] * rn, vv[0][3] * rn),
                        pkc(vv[1][0] * rn, vv[1][1] * rn), pkc(vv[1][2] * rn, vv[1][3] * rn), lane);
      }
    }
    // ---- k: L2-normalize (bias 0), pack -> A-frags ----
    {
      #pragma unroll
      for (int nt = 0; nt < 4; ++nt) {
        float ss = 0.0f;
        #pragma unroll
        for (int dt = 0; dt < 2; ++dt)
          #pragma unroll
          for (int r = 0; r < 4; ++r) ss += sk[dt][nt][r] * sk[dt][nt][r];
        ss += __shfl_xor(ss, 16);
        ss += __shfl_xor(ss, 32);
        float rn = 1.0f / fmaxf(sqrtf(ss), 1e-12f);
        kA[nt] = xposeS(pkc(sk[0][nt][0] * rn, sk[0][nt][1] * rn), pkc(sk[0][nt][2] * rn, sk[0][nt][3] * rn),
                        pkc(sk[1][nt][0] * rn, sk[1][nt][1] * rn), pkc(sk[1][nt][2] * rn, sk[1][nt][3] * rn), lane);
      }
    }
    // ---- v: +bias, pack -> v^T A-frags vA[dt][kt] ----
    {
      const float vb0 = qkvb[512 + h * 32 + lq];
      const float vb1 = qkvb[512 + h * 32 + 16 + lq];
      unsigned vp[4][2][2];
      #pragma unroll
      for (int mt = 0; mt < 4; ++mt) {
        vp[mt][0][0] = pkc(sv[mt][0][0] + vb0, sv[mt][0][1] + vb0);
        vp[mt][0][1] = pkc(sv[mt][0][2] + vb0, sv[mt][0][3] + vb0);
        vp[mt][1][0] = pkc(sv[mt][1][0] + vb1, sv[mt][1][1] + vb1);
        vp[mt][1][1] = pkc(sv[mt][1][2] + vb1, sv[mt][1][3] + vb1);
      }
      #pragma unroll
      for (int dt = 0; dt < 2; ++dt)
        #pragma unroll
        for (int kt = 0; kt < 2; ++kt)
          vA[dt][kt] = xposeS(vp[2 * kt][dt][0], vp[2 * kt][dt][1],
                              vp[2 * kt + 1][dt][0], vp[2 * kt + 1][dt][1], lane);
    }

    // ---- S^T[key][query] = mfma(kA, qB) ----
    f32x4 sT[4][4];
    #pragma unroll
    for (int nt = 0; nt < 4; ++nt)
      #pragma unroll
      for (int mt = 0; mt < 4; ++mt)
        sT[nt][mt] = __builtin_amdgcn_mfma_f32_16x16x32_bf16(kA[nt], qB[mt], fz, 0, 0, 0);

    // ---- softmax over keys (16 in-lane + shfl 16/32); P packed UNNORMALIZED,
    //      per-query inv held in invs[mt] and applied to otk after PV ----
    const float sch = scale[h];
    float invs[4];
    unsigned pp[4][4][2];   // [mt][nt][c]
    #pragma unroll
    for (int mt = 0; mt < 4; ++mt) {
      f32x4 rp[4];
      #pragma unroll
      for (int nt = 0; nt < 4; ++nt)
        rp[nt] = ((const f32x4*)rpb)[((h * 4 + mt) * 4 + nt) * 64 + lane];
      float ee[4][4];
      float mx = -3.0e38f;
      #pragma unroll
      for (int nt = 0; nt < 4; ++nt)
        #pragma unroll
        for (int r = 0; r < 4; ++r) {
          float vv = sT[nt][mt][r] * sch + rp[nt][r];
          ee[nt][r] = vv;
          mx = fmaxf(mx, vv);
        }
      mx = fmaxf(mx, __shfl_xor(mx, 16));
      mx = fmaxf(mx, __shfl_xor(mx, 32));
      float sm = 0.0f;
      #pragma unroll
      for (int nt = 0; nt < 4; ++nt)
        #pragma unroll
        for (int r = 0; r < 4; ++r) {
          ee[nt][r] = __expf(ee[nt][r] - mx);
          sm += ee[nt][r];
        }
      sm += __shfl_xor(sm, 16);
      sm += __shfl_xor(sm, 32);
      invs[mt] = 1.0f / sm;
      #pragma unroll
      for (int nt = 0; nt < 4; ++nt) {
        pp[mt][nt][0] = pkc(ee[nt][0], ee[nt][1]);
        pp[mt][nt][1] = pkc(ee[nt][2], ee[nt][3]);
      }
    }

    // ---- PV: out^T = v^T · P^T -> otk[hi] (held in regs), then scale by invs ----
    #pragma unroll
    for (int dt = 0; dt < 2; ++dt)
      #pragma unroll
      for (int mt = 0; mt < 4; ++mt) otk[hi][dt][mt] = fz;
    #pragma unroll
    for (int kt = 0; kt < 2; ++kt) {
      bf16x8 pB[4];
      #pragma unroll
      for (int mt = 0; mt < 4; ++mt)
        pB[mt] = xposeS(pp[mt][2 * kt][0], pp[mt][2 * kt][1],
                        pp[mt][2 * kt + 1][0], pp[mt][2 * kt + 1][1], lane);
      #pragma unroll
      for (int dt = 0; dt < 2; ++dt)
        #pragma unroll
        for (int mt = 0; mt < 4; ++mt)
          otk[hi][dt][mt] = __builtin_amdgcn_mfma_f32_16x16x32_bf16(vA[dt][kt], pB[mt], otk[hi][dt][mt], 0, 0, 0);
    }
    #pragma unroll
    for (int dt = 0; dt < 2; ++dt)
      #pragma unroll
      for (int mt = 0; mt < 4; ++mt)
        otk[hi][dt][mt] = otk[hi][dt][mt] * invs[mt];
  }  // hi

  // ---- all xb reads done: overlay ob on sbuf (compiler-native packs) ----
  __syncthreads();
  #pragma unroll
  for (int hi = 0; hi < 2; ++hi) {
    const int h = wid + hi * 4;
    #pragma unroll
    for (int dt = 0; dt < 2; ++dt)
      #pragma unroll
      for (int mt = 0; mt < 4; ++mt) {
        union { unsigned u[2]; short4v s; } pk;
        pk.u[0] = pkc(otk[hi][dt][mt][0], otk[hi][dt][mt][1]);
        pk.u[1] = pkc(otk[hi][dt][mt][2], otk[hi][dt][mt][3]);
        *(short4v*)&sbuf[(mt * 16 + lq) * 264 + h * 32 + dt * 16 + lg * 4] = pk.s;
      }
  }
  __syncthreads();

  // ---- proj: out = ob · Wp^T + b (wave w -> cols [w*64, w*64+64)) ----
  {
    f32x4 acc[4][4];
    #pragma unroll
    for (int mt = 0; mt < 4; ++mt)
      #pragma unroll
      for (int nt = 0; nt < 4; ++nt) acc[mt][nt] = fz;
    const int c0 = wid * 64;
    #pragma unroll 2
    for (int ks = 0; ks < 8; ++ks) {
      const int k0 = ks * 32;
      bf16x8 a[4], b[4];
      #pragma unroll
      for (int mt = 0; mt < 4; ++mt)
        a[mt] = *(const bf16x8*)&sbuf[(mt * 16 + lq) * 264 + k0 + lg * 8];
      #pragma unroll
      for (int nt = 0; nt < 4; ++nt)
        b[nt] = *(const bf16x8*)&wproj[(c0 + nt * 16 + lq) * 256 + k0 + lg * 8];
      #pragma unroll
      for (int mt = 0; mt < 4; ++mt)
        #pragma unroll
        for (int nt = 0; nt < 4; ++nt)
          acc[mt][nt] = __builtin_amdgcn_mfma_f32_16x16x32_bf16(a[mt], b[nt], acc[mt][nt], 0, 0, 0);
    }
    #pragma unroll
    for (int nt = 0; nt < 4; ++nt) {
      const float pbv = projb[c0 + nt * 16 + lq];
      #pragma unroll
      for (int mt = 0; mt < 4; ++mt)
        #pragma unroll
        for (int r = 0; r < 4; ++r) {
          const int row = mt * 16 + lg * 4 + r;
          out[((size_t)blk * 64 + row) * 256 + c0 + nt * 16 + lq] = acc[mt][nt][r] + pbv;
        }
    }
  }
}

extern "C" void kernel_launch(void* const* d_in, const int* in_sizes, int n_in,
                              void* d_out, int out_size, void* d_ws, size_t ws_size,
                              hipStream_t stream) {
  const float* x     = (const float*)d_in[0];
  const float* qkvw  = (const float*)d_in[1];
  const float* qbias = (const float*)d_in[2];
  const float* vbias = (const float*)d_in[3];
  const float* ls    = (const float*)d_in[4];
  const float* w1    = (const float*)d_in[5];
  const float* b1    = (const float*)d_in[6];
  const float* w2    = (const float*)d_in[7];
  const float* pw    = (const float*)d_in[8];
  const float* pbias = (const float*)d_in[9];
  float* out = (float*)d_out;

  char* ws = (char*)d_ws;
  short* wqkv_bf  = (short*)(ws);                 // 393216 B
  short* wproj_bf = (short*)(ws + 393216);        // 131072 B
  float* rpb      = (float*)(ws + 524288);        // 131072 B
  float* scale    = (float*)(ws + 655360);        // 32 B
  float* qkvb     = (float*)(ws + 655392);        // 3072 B
  float* bt       = (float*)(ws + 658464);        // 4064 B

  prep_kernel<<<dim3(1151), dim3(256), 0, stream>>>(w1, b1, w2, bt,
                                                    qkvw, pw, qbias, vbias,
                                                    wqkv_bf, wproj_bf, qkvb);
  cpb_expand_kernel<<<dim3(128), dim3(256), 0, stream>>>(bt, ls, rpb, scale);
  win_attn_kernel<<<dim3(2048), dim3(256), 0, stream>>>(x, wqkv_bf, wproj_bf, qkvb,
                                                        scale, rpb, pbias, out);
}

// Round 16
// 178.124 us; speedup vs baseline: 1.0998x; 1.0340x over previous
//
#include <hip/hip_runtime.h>
#include <hip/hip_bf16.h>

// Swin-V2 window attention, fused. B=2048 windows, N=64 tokens, C=256, H=8, Dh=32.
// R16 = R15 (184.2us, PASS) with ONE change: xposeS (8x ds_bpermute) replaced by
// xposeP (4x v_permlane{32,16}_swap_b32, VALU-class). Derivation (ISA semantics):
//   swap32(A,B):  A'=[A0,A1,B0,B1]g, B'=[A2,A3,B2,B3]g
//   swap16(A',B'): A''=[A0,A2,B0,B2]g = out_low, B''=[A1,A3,B1,B3]g = out_high
// which is exactly the required mapping out[w] <- in[lg>>1][w&1] @ group 2(lg&1)+(w>>1).
// R3's NaN is fully attributed to cvt2-on-acc + lb>=3 (R4/R5/R6 isolate both without
// permlane); permlane-at-lb2 is the untested cell this round tests.
// EVIDENCE RULES (R3..R15):
//  - never feed RAW MFMA-accumulator values to inline-asm v_cvt_pk_bf16_f32
//    (0.119 absmax R6/R7). Compiler-native converts (pkc) on acc values are safe.
//  - never use __launch_bounds__ minWavesPerEU >= 3 (NaN with AND without cvt2).
//  - occupancy is register-capped at 2 blocks/CU; lb stays (256,2).
//  - deferred-V global x re-read thrashes L2 (R8) — x staged once in LDS.
//  - LDS bank analysis (R12): all b128 patterns at the 8-dword/bank floor.
//  - setprio / unroll>2: regression (R13).
// Layout algebra (mfma_f32_16x16x32_bf16): C/D: col=lane&15, row=(lane>>4)*4+reg;
// A-frag A[lane&15][(lane>>4)*8+j]; B-frag B[(lane>>4)*8+j][lane&15].

typedef __attribute__((ext_vector_type(8))) short bf16x8;
typedef __attribute__((ext_vector_type(4))) short short4v;
typedef __attribute__((ext_vector_type(4))) float f32x4;

__device__ __forceinline__ unsigned short f2bf(float f) {
  union { float f; unsigned int u; } a; a.f = f;
  return (unsigned short)((a.u + 0x7FFFu + ((a.u >> 16) & 1u)) >> 16);  // RNE
}

// compiler-native packed f32x2 -> bf16x2 (RNE, lo = first/low 16b). Safe on
// accumulator values: no inline asm, compiler manages register classes.
__device__ __forceinline__ unsigned pkc(float lo, float hi) {
  float2 f; f.x = lo; f.y = hi;
  __hip_bfloat162 h = __float22bfloat162_rn(f);
  union { __hip_bfloat162 h; unsigned u; } c; c.h = h;
  return c.u;
}

// packed f32x2 -> bf16x2 inline asm, single VALU instr. ONLY safe on plain-VGPR
// load-path values — see EVIDENCE RULES above.
__device__ __forceinline__ unsigned int cvt2(float lo, float hi) {
  unsigned int r;
  asm("v_cvt_pk_bf16_f32 %0, %1, %2" : "=v"(r) : "v"(lo), "v"(hi));
  return r;
}

// 4x4 u32 transpose across stride-16 lane groups via permlane swaps (VALU).
// in (a0,a1,b0,b1) = in[0][0], in[0][1], in[1][0], in[1][1];
// out words {a0,a1,b0,b1} after swaps = required A/B-frag order.
__device__ __forceinline__ bf16x8 xposeP(unsigned a0, unsigned a1,
                                         unsigned b0, unsigned b1) {
  asm("v_permlane32_swap_b32 %0, %1" : "+v"(a0), "+v"(b0));
  asm("v_permlane16_swap_b32 %0, %1" : "+v"(a0), "+v"(b0));
  asm("v_permlane32_swap_b32 %0, %1" : "+v"(a1), "+v"(b1));
  asm("v_permlane16_swap_b32 %0, %1" : "+v"(a1), "+v"(b1));
  union { unsigned u[4]; bf16x8 v; } c;
  c.u[0] = a0; c.u[1] = a1; c.u[2] = b0; c.u[3] = b1;
  return c.v;
}

// ---------------- fused prep: cpb table (blocks 0..126) + weight convert ----------------
__global__ void prep_kernel(const float* __restrict__ w1, const float* __restrict__ b1,
                            const float* __restrict__ w2, float* __restrict__ bt,
                            const float* __restrict__ qw, const float* __restrict__ pw,
                            const float* __restrict__ qb, const float* __restrict__ vb,
                            short* __restrict__ wqkv, short* __restrict__ wproj,
                            float* __restrict__ qkvb)
{
  if (blockIdx.x < 127) {
    // ---- CPB MLP table row (R9-proven body, first wave only) ----
    if (threadIdx.x < 64) {
      const int row = blockIdx.x;       // 0..126
      const int lane = threadIdx.x;     // 0..63
      float xr = ((float)row - 63.0f) * (8.0f / 63.0f);
      float sgn = (xr > 0.0f) ? 1.0f : ((xr < 0.0f) ? -1.0f : 0.0f);
      float val = sgn * log2f(fabsf(xr) + 1.0f) * (1.0f / 3.0f);  // /log2(8)
      float acc[8];
      #pragma unroll
      for (int hh = 0; hh < 8; ++hh) acc[hh] = 0.0f;
      #pragma unroll
      for (int jj = 0; jj < 8; ++jj) {
        int j = jj * 64 + lane;
        float hv = fmaxf(val * w1[j] + b1[j], 0.0f);
        #pragma unroll
        for (int hh = 0; hh < 8; ++hh) acc[hh] += hv * w2[hh * 512 + j];
      }
      #pragma unroll
      for (int hh = 0; hh < 8; ++hh) {
        #pragma unroll
        for (int m = 1; m < 64; m <<= 1) acc[hh] += __shfl_xor(acc[hh], m);
      }
      if (lane == 0) {
        #pragma unroll
        for (int hh = 0; hh < 8; ++hh) bt[row * 8 + hh] = acc[hh];
      }
    }
  } else {
    // ---- weight conversion (proven formulas, re-based index) ----
    const int idx = (blockIdx.x - 127) * 256 + threadIdx.x;
    if (idx < 196608) wqkv[idx] = (short)f2bf(qw[idx]);
    else if (idx - 196608 < 65536) wproj[idx - 196608] = (short)f2bf(pw[idx - 196608]);
    if (idx < 768) qkvb[idx] = (idx < 256) ? qb[idx] : ((idx < 512) ? 0.0f : vb[idx - 512]);
  }
}

// ---- expand (S^T orientation, R10-proven): rpb[h][mt][nt][lane][r] ----
__global__ void cpb_expand_kernel(const float* __restrict__ bt, const float* __restrict__ ls,
                                  float* __restrict__ rpb, float* __restrict__ scale)
{
  const int i = blockIdx.x * 256 + threadIdx.x;   // 0..32767
  const int r = i & 3, lane = (i >> 2) & 63, nt = (i >> 8) & 3, mt = (i >> 10) & 3, hh = i >> 12;
  const int row_i = mt * 16 + (lane & 15);          // query index
  const int col_j = nt * 16 + (lane >> 4) * 4 + r;  // key index
  float b = bt[(row_i - col_j + 63) * 8 + hh];
  rpb[i] = 16.0f / (1.0f + __expf(-b));
  if (i < 8) scale[i] = __expf(fminf(ls[i], 4.605170185988091f));  // ln(100)
}

// ---------------- fused window attention ----------------
__global__ __launch_bounds__(256, 2) void win_attn_kernel(
    const float* __restrict__ x,
    const short* __restrict__ wqkv,
    const short* __restrict__ wproj,
    const float* __restrict__ qkvb,
    const float* __restrict__ scale,
    const float* __restrict__ rpb,
    const float* __restrict__ projb,
    float* __restrict__ out)
{
  // single 33,792 B buffer: x tile bf16 [token][C] stride 264 during QKV;
  // overlaid by attention-output tile ob (same layout) after the hi loop.
  __shared__ short sbuf[64 * 264];

  const int tid = threadIdx.x;
  const int wid = tid >> 6;
  const int lane = tid & 63;
  const int lq = lane & 15;
  const int lg = lane >> 4;
  const int blk = blockIdx.x;

  const f32x4 fz = {0.0f, 0.0f, 0.0f, 0.0f};

  // ---- stage x tile (64x256 f32 -> bf16 LDS; cvt2 on load path; bank-floor clean) ----
  {
    const int r = tid >> 2;
    const int c0 = (tid & 3) * 64;
    const float4* xg = (const float4*)(x + ((size_t)blk * 64 + r) * 256 + c0);
    short* dst = &sbuf[r * 264 + c0];
    #pragma unroll
    for (int i = 0; i < 16; i += 2) {
      float4 a = xg[i];
      float4 b = xg[i + 1];
      union { unsigned int u[4]; bf16x8 v; } c;
      c.u[0] = cvt2(a.x, a.y); c.u[1] = cvt2(a.z, a.w);
      c.u[2] = cvt2(b.x, b.y); c.u[3] = cvt2(b.z, b.w);
      *(bf16x8*)(dst + i * 4) = c.v;
    }
  }
  __syncthreads();

  f32x4 otk[2][2][4];   // [hi][dt][mt], hi compile-time (R2-proven epilogue hold)

  #pragma unroll
  for (int hi = 0; hi < 2; ++hi) {
    const int h = wid + hi * 4;
    const short* wqb = wqkv + (h * 32 + lq) * 256 + lg * 8;

    // ---- QKV: sq/sk = W · x^T (q^T,k^T C-layout), sv = x · Wv^T (v C-layout) ----
    f32x4 sq[2][4], sk[2][4], sv[4][2];
    #pragma unroll
    for (int i = 0; i < 2; ++i)
      #pragma unroll
      for (int j = 0; j < 4; ++j) { sq[i][j] = fz; sk[i][j] = fz; sv[j][i] = fz; }

    #pragma unroll 2
    for (int ks = 0; ks < 8; ++ks) {
      const int k0 = ks * 32;
      bf16x8 xf[4];
      #pragma unroll
      for (int mt = 0; mt < 4; ++mt)
        xf[mt] = *(const bf16x8*)&sbuf[(mt * 16 + lq) * 264 + k0 + lg * 8];
      bf16x8 wqf[2], wkf[2], wvf[2];
      #pragma unroll
      for (int dt = 0; dt < 2; ++dt) {
        const short* wp = wqb + dt * 4096 + k0;
        wqf[dt] = *(const bf16x8*)wp;
        wkf[dt] = *(const bf16x8*)(wp + 65536);    // +256 rows
        wvf[dt] = *(const bf16x8*)(wp + 131072);   // +512 rows
      }
      #pragma unroll
      for (int dt = 0; dt < 2; ++dt)
        #pragma unroll
        for (int mt = 0; mt < 4; ++mt) {
          sq[dt][mt] = __builtin_amdgcn_mfma_f32_16x16x32_bf16(wqf[dt], xf[mt], sq[dt][mt], 0, 0, 0);
          sk[dt][mt] = __builtin_amdgcn_mfma_f32_16x16x32_bf16(wkf[dt], xf[mt], sk[dt][mt], 0, 0, 0);
          sv[mt][dt] = __builtin_amdgcn_mfma_f32_16x16x32_bf16(xf[mt], wvf[dt], sv[mt][dt], 0, 0, 0);
        }
    }

    bf16x8 qB[4], kA[4], vA[2][2];

    // ---- q: +bias, L2-normalize over d (in-lane 8 + shfl 16/32), pack -> B-frags ----
    {
      float qbias[2][4];
      #pragma unroll
      for (int dt = 0; dt < 2; ++dt)
        #pragma unroll
        for (int r = 0; r < 4; ++r)
          qbias[dt][r] = qkvb[h * 32 + dt * 16 + lg * 4 + r];
      #pragma unroll
      for (int mt = 0; mt < 4; ++mt) {
        float vv[2][4];
        float ss = 0.0f;
        #pragma unroll
        for (int dt = 0; dt < 2; ++dt)
          #pragma unroll
          for (int r = 0; r < 4; ++r) {
            vv[dt][r] = sq[dt][mt][r] + qbias[dt][r];
            ss += vv[dt][r] * vv[dt][r];
          }
        ss += __shfl_xor(ss, 16);
        ss += __shfl_xor(ss, 32);
        float rn = 1.0f / fmaxf(sqrtf(ss), 1e-12f);
        qB[mt] = xposeP(pkc(vv[0][0] * rn, vv[0][1] * rn), pkc(vv[0][2] * rn, vv[0][3] * rn),
                        pkc(vv[1][0] * rn, vv[1][1] * rn), pkc(vv[1][2] * rn, vv[1][3] * rn));
      }
    }
    // ---- k: L2-normalize (bias 0), pack -> A-frags ----
    {
      #pragma unroll
      for (int nt = 0; nt < 4; ++nt) {
        float ss = 0.0f;
        #pragma unroll
        for (int dt = 0; dt < 2; ++dt)
          #pragma unroll
          for (int r = 0; r < 4; ++r) ss += sk[dt][nt][r] * sk[dt][nt][r];
        ss += __shfl_xor(ss, 16);
        ss += __shfl_xor(ss, 32);
        float rn = 1.0f / fmaxf(sqrtf(ss), 1e-12f);
        kA[nt] = xposeP(pkc(sk[0][nt][0] * rn, sk[0][nt][1] * rn), pkc(sk[0][nt][2] * rn, sk[0][nt][3] * rn),
                        pkc(sk[1][nt][0] * rn, sk[1][nt][1] * rn), pkc(sk[1][nt][2] * rn, sk[1][nt][3] * rn));
      }
    }
    // ---- v: +bias, pack -> v^T A-frags vA[dt][kt] ----
    {
      const float vb0 = qkvb[512 + h * 32 + lq];
      const float vb1 = qkvb[512 + h * 32 + 16 + lq];
      unsigned vp[4][2][2];
      #pragma unroll
      for (int mt = 0; mt < 4; ++mt) {
        vp[mt][0][0] = pkc(sv[mt][0][0] + vb0, sv[mt][0][1] + vb0);
        vp[mt][0][1] = pkc(sv[mt][0][2] + vb0, sv[mt][0][3] + vb0);
        vp[mt][1][0] = pkc(sv[mt][1][0] + vb1, sv[mt][1][1] + vb1);
        vp[mt][1][1] = pkc(sv[mt][1][2] + vb1, sv[mt][1][3] + vb1);
      }
      #pragma unroll
      for (int dt = 0; dt < 2; ++dt)
        #pragma unroll
        for (int kt = 0; kt < 2; ++kt)
          vA[dt][kt] = xposeP(vp[2 * kt][dt][0], vp[2 * kt][dt][1],
                              vp[2 * kt + 1][dt][0], vp[2 * kt + 1][dt][1]);
    }

    // ---- S^T[key][query] = mfma(kA, qB) ----
    f32x4 sT[4][4];
    #pragma unroll
    for (int nt = 0; nt < 4; ++nt)
      #pragma unroll
      for (int mt = 0; mt < 4; ++mt)
        sT[nt][mt] = __builtin_amdgcn_mfma_f32_16x16x32_bf16(kA[nt], qB[mt], fz, 0, 0, 0);

    // ---- softmax over keys (16 in-lane + shfl 16/32); P packed UNNORMALIZED,
    //      per-query inv held in invs[mt] and applied to otk after PV ----
    const float sch = scale[h];
    float invs[4];
    unsigned pp[4][4][2];   // [mt][nt][c]
    #pragma unroll
    for (int mt = 0; mt < 4; ++mt) {
      f32x4 rp[4];
      #pragma unroll
      for (int nt = 0; nt < 4; ++nt)
        rp[nt] = ((const f32x4*)rpb)[((h * 4 + mt) * 4 + nt) * 64 + lane];
      float ee[4][4];
      float mx = -3.0e38f;
      #pragma unroll
      for (int nt = 0; nt < 4; ++nt)
        #pragma unroll
        for (int r = 0; r < 4; ++r) {
          float vv = sT[nt][mt][r] * sch + rp[nt][r];
          ee[nt][r] = vv;
          mx = fmaxf(mx, vv);
        }
      mx = fmaxf(mx, __shfl_xor(mx, 16));
      mx = fmaxf(mx, __shfl_xor(mx, 32));
      float sm = 0.0f;
      #pragma unroll
      for (int nt = 0; nt < 4; ++nt)
        #pragma unroll
        for (int r = 0; r < 4; ++r) {
          ee[nt][r] = __expf(ee[nt][r] - mx);
          sm += ee[nt][r];
        }
      sm += __shfl_xor(sm, 16);
      sm += __shfl_xor(sm, 32);
      invs[mt] = 1.0f / sm;
      #pragma unroll
      for (int nt = 0; nt < 4; ++nt) {
        pp[mt][nt][0] = pkc(ee[nt][0], ee[nt][1]);
        pp[mt][nt][1] = pkc(ee[nt][2], ee[nt][3]);
      }
    }

    // ---- PV: out^T = v^T · P^T -> otk[hi] (held in regs), then scale by invs ----
    #pragma unroll
    for (int dt = 0; dt < 2; ++dt)
      #pragma unroll
      for (int mt = 0; mt < 4; ++mt) otk[hi][dt][mt] = fz;
    #pragma unroll
    for (int kt = 0; kt < 2; ++kt) {
      bf16x8 pB[4];
      #pragma unroll
      for (int mt = 0; mt < 4; ++mt)
        pB[mt] = xposeP(pp[mt][2 * kt][0], pp[mt][2 * kt][1],
                        pp[mt][2 * kt + 1][0], pp[mt][2 * kt + 1][1]);
      #pragma unroll
      for (int dt = 0; dt < 2; ++dt)
        #pragma unroll
        for (int mt = 0; mt < 4; ++mt)
          otk[hi][dt][mt] = __builtin_amdgcn_mfma_f32_16x16x32_bf16(vA[dt][kt], pB[mt], otk[hi][dt][mt], 0, 0, 0);
    }
    #pragma unroll
    for (int dt = 0; dt < 2; ++dt)
      #pragma unroll
      for (int mt = 0; mt < 4; ++mt)
        otk[hi][dt][mt] = otk[hi][dt][mt] * invs[mt];
  }  // hi

  // ---- all xb reads done: overlay ob on sbuf (compiler-native packs) ----
  __syncthreads();
  #pragma unroll
  for (int hi = 0; hi < 2; ++hi) {
    const int h = wid + hi * 4;
    #pragma unroll
    for (int dt = 0; dt < 2; ++dt)
      #pragma unroll
      for (int mt = 0; mt < 4; ++mt) {
        union { unsigned u[2]; short4v s; } pk;
        pk.u[0] = pkc(otk[hi][dt][mt][0], otk[hi][dt][mt][1]);
        pk.u[1] = pkc(otk[hi][dt][mt][2], otk[hi][dt][mt][3]);
        *(short4v*)&sbuf[(mt * 16 + lq) * 264 + h * 32 + dt * 16 + lg * 4] = pk.s;
      }
  }
  __syncthreads();

  // ---- proj: out = ob · Wp^T + b (wave w -> cols [w*64, w*64+64)) ----
  {
    f32x4 acc[4][4];
    #pragma unroll
    for (int mt = 0; mt < 4; ++mt)
      #pragma unroll
      for (int nt = 0; nt < 4; ++nt) acc[mt][nt] = fz;
    const int c0 = wid * 64;
    #pragma unroll 2
    for (int ks = 0; ks < 8; ++ks) {
      const int k0 = ks * 32;
      bf16x8 a[4], b[4];
      #pragma unroll
      for (int mt = 0; mt < 4; ++mt)
        a[mt] = *(const bf16x8*)&sbuf[(mt * 16 + lq) * 264 + k0 + lg * 8];
      #pragma unroll
      for (int nt = 0; nt < 4; ++nt)
        b[nt] = *(const bf16x8*)&wproj[(c0 + nt * 16 + lq) * 256 + k0 + lg * 8];
      #pragma unroll
      for (int mt = 0; mt < 4; ++mt)
        #pragma unroll
        for (int nt = 0; nt < 4; ++nt)
          acc[mt][nt] = __builtin_amdgcn_mfma_f32_16x16x32_bf16(a[mt], b[nt], acc[mt][nt], 0, 0, 0);
    }
    #pragma unroll
    for (int nt = 0; nt < 4; ++nt) {
      const float pbv = projb[c0 + nt * 16 + lq];
      #pragma unroll
      for (int mt = 0; mt < 4; ++mt)
        #pragma unroll
        for (int r = 0; r < 4; ++r) {
          const int row = mt * 16 + lg * 4 + r;
          out[((size_t)blk * 64 + row) * 256 + c0 + nt * 16 + lq] = acc[mt][nt][r] + pbv;
        }
    }
  }
}

extern "C" void kernel_launch(void* const* d_in, const int* in_sizes, int n_in,
                              void* d_out, int out_size, void* d_ws, size_t ws_size,
                              hipStream_t stream) {
  const float* x     = (const float*)d_in[0];
  const float* qkvw  = (const float*)d_in[1];
  const float* qbias = (const float*)d_in[2];
  const float* vbias = (const float*)d_in[3];
  const float* ls    = (const float*)d_in[4];
  const float* w1    = (const float*)d_in[5];
  const float* b1    = (const float*)d_in[6];
  const float* w2    = (const float*)d_in[7];
  const float* pw    = (const float*)d_in[8];
  const float* pbias = (const float*)d_in[9];
  float* out = (float*)d_out;

  char* ws = (char*)d_ws;
  short* wqkv_bf  = (short*)(ws);                 // 393216 B
  short* wproj_bf = (short*)(ws + 393216);        // 131072 B
  float* rpb      = (float*)(ws + 524288);        // 131072 B
  float* scale    = (float*)(ws + 655360);        // 32 B
  float* qkvb     = (float*)(ws + 655392);        // 3072 B
  float* bt       = (float*)(ws + 658464);        // 4064 B

  prep_kernel<<<dim3(1151), dim3(256), 0, stream>>>(w1, b1, w2, bt,
                                                    qkvw, pw, qbias, vbias,
                                                    wqkv_bf, wproj_bf, qkvb);
  cpb_expand_kernel<<<dim3(128), dim3(256), 0, stream>>>(bt, ls, rpb, scale);
  win_attn_kernel<<<dim3(2048), dim3(256), 0, stream>>>(x, wqkv_bf, wproj_bf, qkvb,
                                                        scale, rpb, pbias, out);
}